// Round 6
// baseline (600.566 us; speedup 1.0000x reference)
//
#include <hip/hip_runtime.h>

#define NN 100000
#define NE 1600000
#define SF 16
#define DF 32
#define EFT 8
#define HF 64

typedef __attribute__((ext_vector_type(8))) _Float16 half8;
typedef __attribute__((ext_vector_type(4))) _Float16 half4;
typedef __attribute__((ext_vector_type(8))) short short8;
typedef __attribute__((ext_vector_type(4))) float floatx4;

// ---------------- CSR build ----------------
__global__ __launch_bounds__(256) void hist_kernel(const int* __restrict__ ei,
                                                   int* __restrict__ deg) {
  int e = blockIdx.x * 256 + threadIdx.x;
  if (e < NE) atomicAdd(&deg[ei[NE + e]], 1);
}

__global__ __launch_bounds__(256) void scan1_kernel(const int* __restrict__ deg,
                                                    int* __restrict__ cur,
                                                    int* __restrict__ bsums) {
  __shared__ int ts[256];
  int tid = threadIdx.x;
  int base = blockIdx.x * 1024 + tid * 4;
  int v[4];
#pragma unroll
  for (int q = 0; q < 4; ++q) v[q] = (base + q < NN) ? deg[base + q] : 0;
  int s = v[0] + v[1] + v[2] + v[3];
  ts[tid] = s;
  __syncthreads();
  for (int off = 1; off < 256; off <<= 1) {
    int t = (tid >= off) ? ts[tid - off] : 0;
    __syncthreads();
    ts[tid] += t;
    __syncthreads();
  }
  int excl = ts[tid] - s;
  if (tid == 255) bsums[blockIdx.x] = ts[255];
  int run = excl;
#pragma unroll
  for (int q = 0; q < 4; ++q) {
    if (base + q < NN) cur[base + q] = run;
    run += v[q];
  }
}

// scan3 with inline exclusive prefix over block sums (blocks of 256 within
// 1024-wide scan1 tiles: tile id = blockIdx.x>>2, uniform per block)
__global__ __launch_bounds__(256) void scan3_kernel(int* __restrict__ cur,
                                                    const int* __restrict__ bsums) {
  int i = blockIdx.x * 256 + threadIdx.x;
  int g = blockIdx.x >> 2;
  int pref = 0;
  for (int q = 0; q < g; ++q) pref += bsums[q];
  if (i < NN) cur[i] += pref;
}

// ---- setup: zero scattered+deg, build WpreT (f16) and packed W2 frags ----
__global__ __launch_bounds__(256) void setup_kernel(
    const float* __restrict__ W1, const float* __restrict__ W2,
    _Float16* __restrict__ WpreT, _Float16* __restrict__ w2pk,
    float4* __restrict__ scattered4, int* __restrict__ deg) {
  int gid = blockIdx.x * 256 + threadIdx.x;
  if (gid < 800000) {
    float4 z = {0.f, 0.f, 0.f, 0.f};
    scattered4[gid] = z;
  }
  if (gid < NN) deg[gid] = 0;
  if (gid < 128 * 64) {
    int col = gid >> 6, k = gid & 63;
    int j = col & 63;
    bool bh = col >= 64;
    float v = 0.f;
    if (k < 16) v = W1[((bh ? 16 : 0) + k) * HF + j];
    else if (k < 48) v = W1[((bh ? 64 : 32) + (k - 16)) * HF + j];
    WpreT[gid] = (_Float16)v;
  }
  if (gid < 2048) {
    int lane = gid >> 5, idx = gid & 31;
    int kt = idx >> 4, nt = (idx >> 3) & 1, q = idx & 7;
    int kgrp = (lane >> 4) & 3, lcol = lane & 15;
    w2pk[gid] = (_Float16)W2[(kt * 32 + kgrp * 8 + q) * DF + nt * 16 + lcol];
  }
}

// ---- fill: sorted row/col; TP: eaw = ea@W1e + b1 (f16); else ea_s f16 ----
template <bool TP>
__global__ __launch_bounds__(256) void fill_kernel(
    const int* __restrict__ ei, const float* __restrict__ ea,
    const float* __restrict__ W1, const float* __restrict__ b1,
    int* __restrict__ cur, int* __restrict__ row_s, int* __restrict__ col_s,
    _Float16* __restrict__ eaw, _Float16* __restrict__ ea_s) {
  int e = blockIdx.x * 256 + threadIdx.x;
  int r = ei[e];
  int c = ei[NE + e];
  int pos = atomicAdd(&cur[c], 1);
  row_s[pos] = r;
  col_s[pos] = c;
  float eav[8];
  const float4* p = (const float4*)(ea + (size_t)e * EFT);
  float4 v0 = p[0], v1 = p[1];
  eav[0]=v0.x; eav[1]=v0.y; eav[2]=v0.z; eav[3]=v0.w;
  eav[4]=v1.x; eav[5]=v1.y; eav[6]=v1.z; eav[7]=v1.w;
  if constexpr (TP) {
    _Float16* dst = eaw + (size_t)pos * 64;
#pragma unroll 2
    for (int q8 = 0; q8 < 8; ++q8) {
      float acc[8];
#pragma unroll
      for (int jj = 0; jj < 8; ++jj) acc[jj] = b1[q8 * 8 + jj];
#pragma unroll
      for (int t = 0; t < 8; ++t) {
        float x = eav[t];
        const float* w = W1 + (96 + t) * HF + q8 * 8;
#pragma unroll
        for (int jj = 0; jj < 8; ++jj) acc[jj] = fmaf(x, w[jj], acc[jj]);
      }
      half8 h;
#pragma unroll
      for (int jj = 0; jj < 8; ++jj) h[jj] = (_Float16)acc[jj];
      *(half8*)(dst + q8 * 8) = h;
    }
  } else {
    half8 h;
#pragma unroll
    for (int t = 0; t < 8; ++t) h[t] = (_Float16)eav[t];
    *(half8*)(ea_s + (size_t)pos * 8) = h;
  }
}

// ---------------- init: out = x_t @ F[0]; also outb(f16), sums ----------------
__global__ __launch_bounds__(256) void init_kernel(
    const float* __restrict__ x_t, const float* __restrict__ F0,
    float* __restrict__ out, _Float16* __restrict__ outb,
    float* __restrict__ sums) {
  int n = blockIdx.x * 256 + threadIdx.x;
  if (n >= NN) return;
  float x[DF];
  const float4* xr = reinterpret_cast<const float4*>(x_t + (size_t)n * DF);
#pragma unroll
  for (int q = 0; q < 8; ++q) {
    float4 v = xr[q];
    x[4*q+0]=v.x; x[4*q+1]=v.y; x[4*q+2]=v.z; x[4*q+3]=v.w;
  }
  float4* orow = reinterpret_cast<float4*>(out + (size_t)n * DF);
  _Float16* ob = outb + (size_t)n * DF;
  float s = 0.f;
#pragma unroll
  for (int q = 0; q < 8; ++q) {
    float4 acc = {0.f, 0.f, 0.f, 0.f};
#pragma unroll
    for (int i = 0; i < DF; ++i) {
      float xi = x[i];
      acc.x = fmaf(xi, F0[i*DF + 4*q+0], acc.x);
      acc.y = fmaf(xi, F0[i*DF + 4*q+1], acc.y);
      acc.z = fmaf(xi, F0[i*DF + 4*q+2], acc.z);
      acc.w = fmaf(xi, F0[i*DF + 4*q+3], acc.w);
    }
    orow[q] = acc;
    s += acc.x + acc.y + acc.z + acc.w;
    half4 pk = {(_Float16)acc.x, (_Float16)acc.y, (_Float16)acc.z, (_Float16)acc.w};
    *(half4*)(ob + 4*q) = pk;
  }
  sums[n] = s;
}

// ------- pre (f16 MFMA): ABh[n][128] = [xs|out|0] @ Wpre -------
__global__ __launch_bounds__(256, 4) void pre_kernel(
    const float* __restrict__ x_s, const _Float16* __restrict__ outb,
    const _Float16* __restrict__ WpreT, _Float16* __restrict__ ABh) {
  __shared__ _Float16 wlds[128][72];
  int tid = threadIdx.x;
  for (int t = tid; t < 1024; t += 256) {
    int colr = t >> 3, kc = t & 7;
    *(half8*)(&wlds[colr][kc * 8]) = *(const half8*)(WpreT + colr * 64 + kc * 8);
  }
  __syncthreads();

  int lcol = tid & 15, kgrp = (tid >> 4) & 3, wid = tid >> 6;
  int nodebase = blockIdx.x * 64 + wid * 16;
  int nodeA = nodebase + lcol;

  half8 a0 = {}, a1 = {};
  if (nodeA < NN) {
    const _Float16* obp = outb + (size_t)nodeA * DF;
    if (kgrp < 2) {
      const float4* p = (const float4*)(x_s + (size_t)nodeA * SF);
      float4 v0 = p[kgrp * 2], v1 = p[kgrp * 2 + 1];
      a0[0]=(_Float16)v0.x; a0[1]=(_Float16)v0.y;
      a0[2]=(_Float16)v0.z; a0[3]=(_Float16)v0.w;
      a0[4]=(_Float16)v1.x; a0[5]=(_Float16)v1.y;
      a0[6]=(_Float16)v1.z; a0[7]=(_Float16)v1.w;
      a1 = *(const half8*)(obp + 16 + kgrp * 8);
    } else if (kgrp == 2) {
      a0 = *(const half8*)(obp + 0);
    } else {
      a0 = *(const half8*)(obp + 8);
    }
  }

  floatx4 acc[8];
#pragma unroll
  for (int nt = 0; nt < 8; ++nt) {
    half8 b0 = *(const half8*)(&wlds[nt * 16 + lcol][kgrp * 8]);
    half8 b1v = *(const half8*)(&wlds[nt * 16 + lcol][32 + kgrp * 8]);
    floatx4 c = {0.f, 0.f, 0.f, 0.f};
    c = __builtin_amdgcn_mfma_f32_16x16x32_f16(a0, b0, c, 0, 0, 0);
    c = __builtin_amdgcn_mfma_f32_16x16x32_f16(a1, b1v, c, 0, 0, 0);
    acc[nt] = c;
  }

#pragma unroll
  for (int rr = 0; rr < 4; ++rr) {
    int node = nodebase + kgrp * 4 + rr;
    if (node < NN) {
      _Float16* dst = ABh + (size_t)node * 128;
#pragma unroll
      for (int nt = 0; nt < 8; ++nt)
        dst[nt * 16 + lcol] = (_Float16)acc[nt][rr];
    }
  }
}

// ---------------- edge MLP (f16 MFMA) + segmented reduce ----------------
template <bool TP>
__global__ __launch_bounds__(256, 4) void edge_kernel(
    const _Float16* __restrict__ ABh, const _Float16* __restrict__ outb,
    const float* __restrict__ sums, const _Float16* __restrict__ eaw,
    const _Float16* __restrict__ ea_s,
    const int* __restrict__ row_s, const int* __restrict__ col_s,
    const float* __restrict__ W1, const float* __restrict__ b1,
    const float* __restrict__ b2, const _Float16* __restrict__ w2pk,
    float* __restrict__ scattered) {
  __shared__ union { unsigned short h[256][72]; float sh[256][33]; } u;
  __shared__ int scol[256];
  __shared__ int srow[256];
  __shared__ union { float msk[256]; struct { unsigned short l0[256], l1[256]; } seg; } vv;
  __shared__ int wbase[4];
  __shared__ int cnt;

  int tid = threadIdx.x;
  int bbase = blockIdx.x * 256;
  int i = bbase + tid;  // NE % 256 == 0: always valid
  if (tid == 0) cnt = 0;
  int lcol = tid & 15, kgrp = (tid >> 4) & 3, wid = tid >> 6;

  const _Float16* wpp = w2pk + (size_t)(tid & 63) * 32;
  half8 w2f00 = *(const half8*)(wpp);
  half8 w2f01 = *(const half8*)(wpp + 8);
  half8 w2f10 = *(const half8*)(wpp + 16);
  half8 w2f11 = *(const half8*)(wpp + 24);
  float b2c0 = b2[lcol], b2c1 = b2[16 + lcol];

  int r = row_s[i];
  int c = col_s[i];
  scol[tid] = c;
  srow[tid] = r;
  float s_r = sums[r], s_c = sums[c];
  vv.msk[tid] = (s_r == 0.f && s_c == 0.f) ? 0.f : 1.f;

  // ---- phase 1: h = relu(A[r] + B[c] + eaw) in packed f16 -> LDS ----
  const _Float16* ar = ABh + (size_t)r * 128;
  const _Float16* bc = ABh + (size_t)c * 128 + 64;
  if constexpr (TP) {
    const _Float16* ew = eaw + (size_t)i * 64;
#pragma unroll 4
    for (int q = 0; q < 8; ++q) {
      half8 a = *(const half8*)(ar + q * 8);
      half8 b = *(const half8*)(bc + q * 8);
      half8 w = *(const half8*)(ew + q * 8);
      half8 s = a + b + w;
      short8 sb = __builtin_bit_cast(short8, s);
      short8 m = sb >> 15;
      sb = sb & ~m;  // relu: zero negatives (and -0)
      *(short8*)(&u.h[tid][q * 8]) = sb;
    }
  } else {
    float eav[8];
    half8 ev = *(const half8*)(ea_s + (size_t)i * 8);
#pragma unroll
    for (int t = 0; t < 8; ++t) eav[t] = (float)ev[t];
#pragma unroll 1
    for (int q = 0; q < 8; ++q) {
      half8 a = *(const half8*)(ar + q * 8);
      half8 b = *(const half8*)(bc + q * 8);
      half8 hh;
#pragma unroll
      for (int jj = 0; jj < 8; ++jj) {
        int j = q * 8 + jj;
        float cj = b1[j];
#pragma unroll
        for (int t = 0; t < 8; ++t) cj = fmaf(eav[t], W1[(96 + t) * HF + j], cj);
        float hv = fmaxf((float)a[jj] + (float)b[jj] + cj, 0.f);
        hh[jj] = (_Float16)hv;
      }
      *(half8*)(&u.h[tid][q * 8]) = hh;
    }
  }
  __syncthreads();

  // ---- phase 2: MFMA, 4 groups of 16 edges per wave ----
  floatx4 acc[4][2];
#pragma unroll
  for (int g = 0; g < 4; ++g) {
    int erow = wid * 64 + g * 16 + lcol;
    half8 a0 = *(const half8*)(&u.h[erow][kgrp * 8]);
    half8 a1 = *(const half8*)(&u.h[erow][32 + kgrp * 8]);
    floatx4 c0 = {b2c0, b2c0, b2c0, b2c0};
    floatx4 c1 = {b2c1, b2c1, b2c1, b2c1};
    c0 = __builtin_amdgcn_mfma_f32_16x16x32_f16(a0, w2f00, c0, 0, 0, 0);
    c0 = __builtin_amdgcn_mfma_f32_16x16x32_f16(a1, w2f10, c0, 0, 0, 0);
    c1 = __builtin_amdgcn_mfma_f32_16x16x32_f16(a0, w2f01, c1, 0, 0, 0);
    c1 = __builtin_amdgcn_mfma_f32_16x16x32_f16(a1, w2f11, c1, 0, 0, 0);
    acc[g][0] = c0;
    acc[g][1] = c1;
  }
  __syncthreads();  // all h reads done; sh (union) may be written now

  // ---- phase 3: norm + mask + shift, C-frag layout ----
#pragma unroll
  for (int g = 0; g < 4; ++g) {
    float nsq[4];
#pragma unroll
    for (int rr = 0; rr < 4; ++rr)
      nsq[rr] = acc[g][0][rr]*acc[g][0][rr] + acc[g][1][rr]*acc[g][1][rr];
#pragma unroll
    for (int mm = 1; mm <= 8; mm <<= 1) {
#pragma unroll
      for (int rr = 0; rr < 4; ++rr)
        nsq[rr] += __shfl_xor(nsq[rr], mm, 64);
    }
#pragma unroll
    for (int rr = 0; rr < 4; ++rr) {
      int e = wid * 64 + g * 16 + kgrp * 4 + rr;
      float ms = (nsq[rr] > 0.f) ? rsqrtf(nsq[rr]) : 0.f;
      ms *= vv.msk[e];
      int r2 = srow[e];
      int c2 = scol[e];
      float ar0 = (float)outb[(size_t)r2 * DF + lcol];
      float ar1 = (float)outb[(size_t)r2 * DF + 16 + lcol];
      float bc0 = (float)outb[(size_t)c2 * DF + lcol];
      float bc1 = (float)outb[(size_t)c2 * DF + 16 + lcol];
      u.sh[e][lcol]      = (bc0 - ar0) * acc[g][0][rr] * ms;
      u.sh[e][16 + lcol] = (bc1 - ar1) * acc[g][1][rr] * ms;
    }
  }
  __syncthreads();

  // ---- phase 4: segmented reduce over sorted-col runs ----
  int c_self = scol[tid];
  bool head = (tid == 0 || scol[tid - 1] != c_self);
  unsigned long long m = __ballot(head);
  int lane = tid & 63;
  if (lane == 0) wbase[wid] = atomicAdd(&cnt, (int)__popcll(m));
  __syncthreads();
  if (head) {
    int idx = wbase[wid] + (int)__popcll(m & ((1ull << lane) - 1ull));
    int t1 = tid + 1;
    while (t1 < 256 && scol[t1] == c_self) ++t1;
    vv.seg.l0[idx] = (unsigned short)tid;
    vv.seg.l1[idx] = (unsigned short)t1;
  }
  __syncthreads();
  int nr = cnt;
  for (int task = tid; task < nr * 32; task += 256) {
    int rid = task >> 5, j = task & 31;
    int t0 = vv.seg.l0[rid], t1 = vv.seg.l1[rid];
    float s = 0.f;
    for (int t = t0; t < t1; ++t) s += u.sh[t][j];
    unsafeAtomicAdd(&scattered[(size_t)scol[t0] * DF + j], s);
  }
}

// --- node update (in place): out += scattered @ Fk; outb/sums; clear sc ---
__global__ __launch_bounds__(256) void node_kernel(
    float* __restrict__ out, float* __restrict__ scattered,
    const float* __restrict__ Fk, _Float16* __restrict__ outb,
    float* __restrict__ sums) {
  int n = blockIdx.x * 256 + threadIdx.x;
  if (n >= NN) return;
  float s[DF];
  float4* sp = reinterpret_cast<float4*>(scattered + (size_t)n * DF);
#pragma unroll
  for (int q = 0; q < 8; ++q) {
    float4 v = sp[q];
    s[4*q+0]=v.x; s[4*q+1]=v.y; s[4*q+2]=v.z; s[4*q+3]=v.w;
  }
  float4* op = reinterpret_cast<float4*>(out + (size_t)n * DF);
  _Float16* ob = outb + (size_t)n * DF;
  float ssum = 0.f;
#pragma unroll
  for (int q = 0; q < 8; ++q) {
    float4 acc = op[q];
#pragma unroll
    for (int i = 0; i < DF; ++i) {
      float si = s[i];
      acc.x = fmaf(si, Fk[i*DF + 4*q+0], acc.x);
      acc.y = fmaf(si, Fk[i*DF + 4*q+1], acc.y);
      acc.z = fmaf(si, Fk[i*DF + 4*q+2], acc.z);
      acc.w = fmaf(si, Fk[i*DF + 4*q+3], acc.w);
    }
    op[q] = acc;
    ssum += acc.x + acc.y + acc.z + acc.w;
    half4 pk = {(_Float16)acc.x, (_Float16)acc.y, (_Float16)acc.z, (_Float16)acc.w};
    *(half4*)(ob + 4*q) = pk;
  }
  sums[n] = ssum;
  float4 z = {0.f, 0.f, 0.f, 0.f};
#pragma unroll
  for (int q = 0; q < 8; ++q) sp[q] = z;
}

extern "C" void kernel_launch(void* const* d_in, const int* in_sizes, int n_in,
                              void* d_out, int out_size, void* d_ws, size_t ws_size,
                              hipStream_t stream) {
  const float* x_s = (const float*)d_in[0];
  const float* x_t = (const float*)d_in[1];
  const int*   ei  = (const int*)d_in[2];
  const float* ea  = (const float*)d_in[3];
  const float* W1  = (const float*)d_in[4];
  const float* b1  = (const float*)d_in[5];
  const float* W2  = (const float*)d_in[6];
  const float* b2  = (const float*)d_in[7];
  const float* F   = (const float*)d_in[8];

  float* out = (float*)d_out;
  char* ws = (char*)d_ws;
  float*     scattered = (float*)(ws);                  // 12.8 MB
  _Float16*  ABh       = (_Float16*)(ws + 12800000);    // 25.6 MB
  _Float16*  outb      = (_Float16*)(ws + 38400000);    // 6.4 MB
  float*     sums      = (float*)(ws + 44800000);       // 0.4 MB
  int*       row_s     = (int*)(ws + 45200000);         // 6.4 MB
  int*       col_s     = (int*)(ws + 51600000);         // 6.4 MB
  int*       deg       = (int*)(ws + 58000000);         // 0.4 MB
  int*       cur       = (int*)(ws + 58400000);         // 0.4 MB
  int*       bsums     = (int*)(ws + 58800000);         // 4 KB
  _Float16*  WpreT     = (_Float16*)(ws + 58810000);    // 16 KB
  _Float16*  w2pk      = (_Float16*)(ws + 58830000);    // 4 KB
  _Float16*  eaw       = (_Float16*)(ws + 58900000);    // 204.8 MB (table path)
  _Float16*  ea_s      = (_Float16*)(ws + 58900000);    // 25.6 MB (fallback)

  bool tp = ws_size >= 263700000ull;

  dim3 blk(256);
  dim3 grid_e(NE / 256);          // 6250, exact
  dim3 grid_n((NN + 255) / 256);  // 391
  dim3 grid_p((NN + 63) / 64);    // 1563
  int nscan = (NN + 1023) / 1024; // 98

  setup_kernel<<<3125, blk, 0, stream>>>(W1, W2, WpreT, w2pk,
                                         (float4*)scattered, deg);
  hist_kernel<<<grid_e, blk, 0, stream>>>(ei, deg);
  scan1_kernel<<<nscan, blk, 0, stream>>>(deg, cur, bsums);
  scan3_kernel<<<grid_n, blk, 0, stream>>>(cur, bsums);
  if (tp)
    fill_kernel<true><<<grid_e, blk, 0, stream>>>(ei, ea, W1, b1, cur,
                                                  row_s, col_s, eaw, ea_s);
  else
    fill_kernel<false><<<grid_e, blk, 0, stream>>>(ei, ea, W1, b1, cur,
                                                   row_s, col_s, eaw, ea_s);

  init_kernel<<<grid_n, blk, 0, stream>>>(x_t, F, out, outb, sums);

  for (int k = 0; k < 2; ++k) {
    pre_kernel<<<grid_p, blk, 0, stream>>>(x_s, outb, WpreT, ABh);
    if (tp)
      edge_kernel<true><<<grid_e, blk, 0, stream>>>(ABh, outb, sums, eaw, ea_s,
                                                    row_s, col_s, W1, b1, b2,
                                                    w2pk, scattered);
    else
      edge_kernel<false><<<grid_e, blk, 0, stream>>>(ABh, outb, sums, eaw, ea_s,
                                                     row_s, col_s, W1, b1, b2,
                                                     w2pk, scattered);
    node_kernel<<<grid_n, blk, 0, stream>>>(out, scattered,
                                            F + (size_t)(k + 1) * DF * DF,
                                            outb, sums);
  }
}

// Round 7
// 452.292 us; speedup vs baseline: 1.3278x; 1.3278x over previous
//
#include <hip/hip_runtime.h>

#define NN 100000
#define NE 1600000
#define SF 16
#define DF 32
#define EFT 8
#define HF 64

typedef __attribute__((ext_vector_type(8))) _Float16 half8;
typedef __attribute__((ext_vector_type(4))) _Float16 half4;
typedef __attribute__((ext_vector_type(8))) short short8;
typedef __attribute__((ext_vector_type(4))) float floatx4;

// ---------------- CSR build ----------------
__global__ __launch_bounds__(256) void hist_kernel(const int* __restrict__ ei,
                                                   int* __restrict__ deg) {
  int e = blockIdx.x * 256 + threadIdx.x;
  if (e < NE) atomicAdd(&deg[ei[NE + e]], 1);
}

__global__ __launch_bounds__(256) void scan1_kernel(const int* __restrict__ deg,
                                                    int* __restrict__ cur,
                                                    int* __restrict__ bsums) {
  __shared__ int ts[256];
  int tid = threadIdx.x;
  int base = blockIdx.x * 1024 + tid * 4;
  int v[4];
#pragma unroll
  for (int q = 0; q < 4; ++q) v[q] = (base + q < NN) ? deg[base + q] : 0;
  int s = v[0] + v[1] + v[2] + v[3];
  ts[tid] = s;
  __syncthreads();
  for (int off = 1; off < 256; off <<= 1) {
    int t = (tid >= off) ? ts[tid - off] : 0;
    __syncthreads();
    ts[tid] += t;
    __syncthreads();
  }
  int excl = ts[tid] - s;
  if (tid == 255) bsums[blockIdx.x] = ts[255];
  int run = excl;
#pragma unroll
  for (int q = 0; q < 4; ++q) {
    if (base + q < NN) cur[base + q] = run;
    run += v[q];
  }
}

// scan3 with inline exclusive prefix over 1024-wide scan1 tile sums
__global__ __launch_bounds__(256) void scan3_kernel(int* __restrict__ cur,
                                                    const int* __restrict__ bsums) {
  int i = blockIdx.x * 256 + threadIdx.x;
  int g = blockIdx.x >> 2;
  int pref = 0;
  for (int q = 0; q < g; ++q) pref += bsums[q];
  if (i < NN) cur[i] += pref;
}

// ---- setup: zero scattered+deg; pack WpreT, W2 frags, W1e frags (f16) ----
__global__ __launch_bounds__(256) void setup_kernel(
    const float* __restrict__ W1, const float* __restrict__ W2,
    _Float16* __restrict__ WpreT, _Float16* __restrict__ w2pk,
    _Float16* __restrict__ w1epk,
    float4* __restrict__ scattered4, int* __restrict__ deg) {
  int gid = blockIdx.x * 256 + threadIdx.x;
  if (gid < 800000) {
    float4 z = {0.f, 0.f, 0.f, 0.f};
    scattered4[gid] = z;
  }
  if (gid < NN) deg[gid] = 0;
  if (gid < 128 * 64) {
    int col = gid >> 6, k = gid & 63;
    int j = col & 63;
    bool bh = col >= 64;
    float v = 0.f;
    if (k < 16) v = W1[((bh ? 16 : 0) + k) * HF + j];
    else if (k < 48) v = W1[((bh ? 64 : 32) + (k - 16)) * HF + j];
    WpreT[gid] = (_Float16)v;
  }
  if (gid < 2048) {
    // W2 B-frags: lane holds col = nt*16+lcol, k = kt*32 + kgrp*8 + q
    int lane = gid >> 5, idx = gid & 31;
    int kt = idx >> 4, nt = (idx >> 3) & 1, q = idx & 7;
    int kgrp = (lane >> 4) & 3, lcol = lane & 15;
    w2pk[gid] = (_Float16)W2[(kt * 32 + kgrp * 8 + q) * DF + nt * 16 + lcol];
  } else if (gid < 4096) {
    // W1e B-frags (K=8 in lanes 0..15, zero elsewhere): idx = nt*8 + j
    int id = gid - 2048;
    int lane = id >> 5, idx = id & 31;
    int nt = idx >> 3, j = idx & 7;
    int lcol = lane & 15;
    float v = (lane < 16) ? W1[(96 + j) * HF + nt * 16 + lcol] : 0.f;
    w1epk[id] = (_Float16)v;
  }
}

// ---- fill: sorted row/col + ea_s (f16, sorted order) ----
__global__ __launch_bounds__(256) void fill_kernel(
    const int* __restrict__ ei, const float* __restrict__ ea,
    int* __restrict__ cur, int* __restrict__ row_s, int* __restrict__ col_s,
    _Float16* __restrict__ ea_s) {
  int e = blockIdx.x * 256 + threadIdx.x;
  int r = ei[e];
  int c = ei[NE + e];
  int pos = atomicAdd(&cur[c], 1);
  row_s[pos] = r;
  col_s[pos] = c;
  const float4* p = (const float4*)(ea + (size_t)e * EFT);
  float4 v0 = p[0], v1 = p[1];
  half8 h;
  h[0]=(_Float16)v0.x; h[1]=(_Float16)v0.y; h[2]=(_Float16)v0.z; h[3]=(_Float16)v0.w;
  h[4]=(_Float16)v1.x; h[5]=(_Float16)v1.y; h[6]=(_Float16)v1.z; h[7]=(_Float16)v1.w;
  *(half8*)(ea_s + (size_t)pos * 8) = h;
}

// ---------------- init: out = x_t @ F[0]; also outb(f16), sums ----------------
__global__ __launch_bounds__(256) void init_kernel(
    const float* __restrict__ x_t, const float* __restrict__ F0,
    float* __restrict__ out, _Float16* __restrict__ outb,
    float* __restrict__ sums) {
  int n = blockIdx.x * 256 + threadIdx.x;
  if (n >= NN) return;
  float x[DF];
  const float4* xr = reinterpret_cast<const float4*>(x_t + (size_t)n * DF);
#pragma unroll
  for (int q = 0; q < 8; ++q) {
    float4 v = xr[q];
    x[4*q+0]=v.x; x[4*q+1]=v.y; x[4*q+2]=v.z; x[4*q+3]=v.w;
  }
  float4* orow = reinterpret_cast<float4*>(out + (size_t)n * DF);
  _Float16* ob = outb + (size_t)n * DF;
  float s = 0.f;
#pragma unroll
  for (int q = 0; q < 8; ++q) {
    float4 acc = {0.f, 0.f, 0.f, 0.f};
#pragma unroll
    for (int i = 0; i < DF; ++i) {
      float xi = x[i];
      acc.x = fmaf(xi, F0[i*DF + 4*q+0], acc.x);
      acc.y = fmaf(xi, F0[i*DF + 4*q+1], acc.y);
      acc.z = fmaf(xi, F0[i*DF + 4*q+2], acc.z);
      acc.w = fmaf(xi, F0[i*DF + 4*q+3], acc.w);
    }
    orow[q] = acc;
    s += acc.x + acc.y + acc.z + acc.w;
    half4 pk = {(_Float16)acc.x, (_Float16)acc.y, (_Float16)acc.z, (_Float16)acc.w};
    *(half4*)(ob + 4*q) = pk;
  }
  sums[n] = s;
}

// ------- pre (f16 MFMA): ABh[n][128] = [xs|out|0] @ Wpre -------
__global__ __launch_bounds__(256, 4) void pre_kernel(
    const float* __restrict__ x_s, const _Float16* __restrict__ outb,
    const _Float16* __restrict__ WpreT, _Float16* __restrict__ ABh) {
  __shared__ _Float16 wlds[128][72];
  int tid = threadIdx.x;
  for (int t = tid; t < 1024; t += 256) {
    int colr = t >> 3, kc = t & 7;
    *(half8*)(&wlds[colr][kc * 8]) = *(const half8*)(WpreT + colr * 64 + kc * 8);
  }
  __syncthreads();

  int lcol = tid & 15, kgrp = (tid >> 4) & 3, wid = tid >> 6;
  int nodebase = blockIdx.x * 64 + wid * 16;
  int nodeA = nodebase + lcol;

  half8 a0 = {}, a1 = {};
  if (nodeA < NN) {
    const _Float16* obp = outb + (size_t)nodeA * DF;
    if (kgrp < 2) {
      const float4* p = (const float4*)(x_s + (size_t)nodeA * SF);
      float4 v0 = p[kgrp * 2], v1 = p[kgrp * 2 + 1];
      a0[0]=(_Float16)v0.x; a0[1]=(_Float16)v0.y;
      a0[2]=(_Float16)v0.z; a0[3]=(_Float16)v0.w;
      a0[4]=(_Float16)v1.x; a0[5]=(_Float16)v1.y;
      a0[6]=(_Float16)v1.z; a0[7]=(_Float16)v1.w;
      a1 = *(const half8*)(obp + 16 + kgrp * 8);
    } else if (kgrp == 2) {
      a0 = *(const half8*)(obp + 0);
    } else {
      a0 = *(const half8*)(obp + 8);
    }
  }

  floatx4 acc[8];
#pragma unroll
  for (int nt = 0; nt < 8; ++nt) {
    half8 b0 = *(const half8*)(&wlds[nt * 16 + lcol][kgrp * 8]);
    half8 b1v = *(const half8*)(&wlds[nt * 16 + lcol][32 + kgrp * 8]);
    floatx4 c = {0.f, 0.f, 0.f, 0.f};
    c = __builtin_amdgcn_mfma_f32_16x16x32_f16(a0, b0, c, 0, 0, 0);
    c = __builtin_amdgcn_mfma_f32_16x16x32_f16(a1, b1v, c, 0, 0, 0);
    acc[nt] = c;
  }

#pragma unroll
  for (int rr = 0; rr < 4; ++rr) {
    int node = nodebase + kgrp * 4 + rr;
    if (node < NN) {
      _Float16* dst = ABh + (size_t)node * 128;
#pragma unroll
      for (int nt = 0; nt < 8; ++nt)
        dst[nt * 16 + lcol] = (_Float16)acc[nt][rr];
    }
  }
}

// ---------------- edge MLP (f16 MFMA, in-LDS ea-projection) ----------------
__global__ __launch_bounds__(256, 4) void edge_kernel(
    const _Float16* __restrict__ ABh, const _Float16* __restrict__ outb,
    const float* __restrict__ sums, const _Float16* __restrict__ ea_s,
    const int* __restrict__ row_s, const int* __restrict__ col_s,
    const float* __restrict__ b1, const float* __restrict__ b2,
    const _Float16* __restrict__ w2pk, const _Float16* __restrict__ w1epk,
    float* __restrict__ scattered) {
  __shared__ union { _Float16 h[256][72]; float sh[256][33]; } u;
  __shared__ int scol[256];
  __shared__ int srow[256];
  __shared__ union { float msk[256]; struct { unsigned short l0[256], l1[256]; } seg; } vv;
  __shared__ int wbase[4];
  __shared__ int cnt;

  int tid = threadIdx.x;
  int bbase = blockIdx.x * 256;
  int i = bbase + tid;  // NE % 256 == 0: always valid
  if (tid == 0) cnt = 0;
  int lcol = tid & 15, kgrp = (tid >> 4) & 3, wid = tid >> 6;
  int lane = tid & 63;

  const _Float16* wpp = w2pk + (size_t)lane * 32;
  half8 w2f00 = *(const half8*)(wpp);
  half8 w2f01 = *(const half8*)(wpp + 8);
  half8 w2f10 = *(const half8*)(wpp + 16);
  half8 w2f11 = *(const half8*)(wpp + 24);
  float b2c0 = b2[lcol], b2c1 = b2[16 + lcol];

  int r = row_s[i];
  int c = col_s[i];
  scol[tid] = c;
  srow[tid] = r;
  float s_r = sums[r], s_c = sums[c];
  vv.msk[tid] = (s_r == 0.f && s_c == 0.f) ? 0.f : 1.f;

  // ---- phase 0: eaw = ea @ W1e + b1 via MFMA (K=8 in lanes 0..15) -> u.h ----
  half8 eav = *(const half8*)(ea_s + (size_t)i * 8);
  const _Float16* wep = w1epk + (size_t)lane * 32;
  half8 we0 = *(const half8*)(wep);
  half8 we1 = *(const half8*)(wep + 8);
  half8 we2 = *(const half8*)(wep + 16);
  half8 we3 = *(const half8*)(wep + 24);
  float b1c[4] = {b1[lcol], b1[16 + lcol], b1[32 + lcol], b1[48 + lcol]};
  int4 eai = __builtin_bit_cast(int4, eav);
  bool lo16 = lane < 16;
  int rbase0 = wid * 64 + kgrp * 4;
#pragma unroll
  for (int g = 0; g < 4; ++g) {
    int src = g * 16 + lcol;
    int4 t;
    t.x = __shfl(eai.x, src, 64);
    t.y = __shfl(eai.y, src, 64);
    t.z = __shfl(eai.z, src, 64);
    t.w = __shfl(eai.w, src, 64);
    half8 zz = {};
    half8 ag = lo16 ? __builtin_bit_cast(half8, t) : zz;
#pragma unroll
    for (int nt = 0; nt < 4; ++nt) {
      floatx4 cc = {b1c[nt], b1c[nt], b1c[nt], b1c[nt]};
      half8 wb = (nt == 0) ? we0 : (nt == 1) ? we1 : (nt == 2) ? we2 : we3;
      cc = __builtin_amdgcn_mfma_f32_16x16x32_f16(ag, wb, cc, 0, 0, 0);
      int rb = rbase0 + g * 16;
#pragma unroll
      for (int rr = 0; rr < 4; ++rr)
        u.h[rb + rr][nt * 16 + lcol] = (_Float16)cc[rr];
    }
  }
  __syncthreads();

  // ---- phase 1: h = relu(A[r] + B[c] + eaw) packed f16, RMW on u.h[tid] ----
  const _Float16* ar = ABh + (size_t)r * 128;
  const _Float16* bc = ABh + (size_t)c * 128 + 64;
#pragma unroll 4
  for (int q = 0; q < 8; ++q) {
    half8 a = *(const half8*)(ar + q * 8);
    half8 b = *(const half8*)(bc + q * 8);
    half8 w = *(const half8*)(&u.h[tid][q * 8]);
    half8 s = a + b + w;
    short8 sb = __builtin_bit_cast(short8, s);
    short8 m = sb >> 15;
    sb = sb & ~m;  // relu: zero negatives (and -0)
    *(short8*)(&u.h[tid][q * 8]) = sb;
  }
  __syncthreads();

  // ---- phase 2: layer-2 MFMA, 4 groups of 16 edges per wave ----
  floatx4 acc[4][2];
#pragma unroll
  for (int g = 0; g < 4; ++g) {
    int erow = wid * 64 + g * 16 + lcol;
    half8 a0 = *(const half8*)(&u.h[erow][kgrp * 8]);
    half8 a1 = *(const half8*)(&u.h[erow][32 + kgrp * 8]);
    floatx4 c0 = {b2c0, b2c0, b2c0, b2c0};
    floatx4 c1 = {b2c1, b2c1, b2c1, b2c1};
    c0 = __builtin_amdgcn_mfma_f32_16x16x32_f16(a0, w2f00, c0, 0, 0, 0);
    c0 = __builtin_amdgcn_mfma_f32_16x16x32_f16(a1, w2f10, c0, 0, 0, 0);
    c1 = __builtin_amdgcn_mfma_f32_16x16x32_f16(a0, w2f01, c1, 0, 0, 0);
    c1 = __builtin_amdgcn_mfma_f32_16x16x32_f16(a1, w2f11, c1, 0, 0, 0);
    acc[g][0] = c0;
    acc[g][1] = c1;
  }
  __syncthreads();  // all h reads done; sh (union) may be written now

  // ---- phase 3: norm + mask + shift, C-frag layout ----
#pragma unroll
  for (int g = 0; g < 4; ++g) {
    float nsq[4];
#pragma unroll
    for (int rr = 0; rr < 4; ++rr)
      nsq[rr] = acc[g][0][rr]*acc[g][0][rr] + acc[g][1][rr]*acc[g][1][rr];
#pragma unroll
    for (int mm = 1; mm <= 8; mm <<= 1) {
#pragma unroll
      for (int rr = 0; rr < 4; ++rr)
        nsq[rr] += __shfl_xor(nsq[rr], mm, 64);
    }
#pragma unroll
    for (int rr = 0; rr < 4; ++rr) {
      int e = wid * 64 + g * 16 + kgrp * 4 + rr;
      float ms = (nsq[rr] > 0.f) ? rsqrtf(nsq[rr]) : 0.f;
      ms *= vv.msk[e];
      int r2 = srow[e];
      int c2 = scol[e];
      float ar0 = (float)outb[(size_t)r2 * DF + lcol];
      float ar1 = (float)outb[(size_t)r2 * DF + 16 + lcol];
      float bc0 = (float)outb[(size_t)c2 * DF + lcol];
      float bc1 = (float)outb[(size_t)c2 * DF + 16 + lcol];
      u.sh[e][lcol]      = (bc0 - ar0) * acc[g][0][rr] * ms;
      u.sh[e][16 + lcol] = (bc1 - ar1) * acc[g][1][rr] * ms;
    }
  }
  __syncthreads();

  // ---- phase 4: segmented reduce over sorted-col runs ----
  int c_self = scol[tid];
  bool head = (tid == 0 || scol[tid - 1] != c_self);
  unsigned long long m = __ballot(head);
  if (lane == 0) wbase[wid] = atomicAdd(&cnt, (int)__popcll(m));
  __syncthreads();
  if (head) {
    int idx = wbase[wid] + (int)__popcll(m & ((1ull << lane) - 1ull));
    int t1 = tid + 1;
    while (t1 < 256 && scol[t1] == c_self) ++t1;
    vv.seg.l0[idx] = (unsigned short)tid;
    vv.seg.l1[idx] = (unsigned short)t1;
  }
  __syncthreads();
  int nr = cnt;
  for (int task = tid; task < nr * 32; task += 256) {
    int rid = task >> 5, j = task & 31;
    int t0 = vv.seg.l0[rid], t1 = vv.seg.l1[rid];
    float s = 0.f;
    for (int t = t0; t < t1; ++t) s += u.sh[t][j];
    unsafeAtomicAdd(&scattered[(size_t)scol[t0] * DF + j], s);
  }
}

// --- node update (in place): out += scattered @ Fk; outb/sums; clear sc ---
__global__ __launch_bounds__(256) void node_kernel(
    float* __restrict__ out, float* __restrict__ scattered,
    const float* __restrict__ Fk, _Float16* __restrict__ outb,
    float* __restrict__ sums) {
  int n = blockIdx.x * 256 + threadIdx.x;
  if (n >= NN) return;
  float s[DF];
  float4* sp = reinterpret_cast<float4*>(scattered + (size_t)n * DF);
#pragma unroll
  for (int q = 0; q < 8; ++q) {
    float4 v = sp[q];
    s[4*q+0]=v.x; s[4*q+1]=v.y; s[4*q+2]=v.z; s[4*q+3]=v.w;
  }
  float4* op = reinterpret_cast<float4*>(out + (size_t)n * DF);
  _Float16* ob = outb + (size_t)n * DF;
  float ssum = 0.f;
#pragma unroll
  for (int q = 0; q < 8; ++q) {
    float4 acc = op[q];
#pragma unroll
    for (int i = 0; i < DF; ++i) {
      float si = s[i];
      acc.x = fmaf(si, Fk[i*DF + 4*q+0], acc.x);
      acc.y = fmaf(si, Fk[i*DF + 4*q+1], acc.y);
      acc.z = fmaf(si, Fk[i*DF + 4*q+2], acc.z);
      acc.w = fmaf(si, Fk[i*DF + 4*q+3], acc.w);
    }
    op[q] = acc;
    ssum += acc.x + acc.y + acc.z + acc.w;
    half4 pk = {(_Float16)acc.x, (_Float16)acc.y, (_Float16)acc.z, (_Float16)acc.w};
    *(half4*)(ob + 4*q) = pk;
  }
  sums[n] = ssum;
  float4 z = {0.f, 0.f, 0.f, 0.f};
#pragma unroll
  for (int q = 0; q < 8; ++q) sp[q] = z;
}

extern "C" void kernel_launch(void* const* d_in, const int* in_sizes, int n_in,
                              void* d_out, int out_size, void* d_ws, size_t ws_size,
                              hipStream_t stream) {
  const float* x_s = (const float*)d_in[0];
  const float* x_t = (const float*)d_in[1];
  const int*   ei  = (const int*)d_in[2];
  const float* ea  = (const float*)d_in[3];
  const float* W1  = (const float*)d_in[4];
  const float* b1  = (const float*)d_in[5];
  const float* W2  = (const float*)d_in[6];
  const float* b2  = (const float*)d_in[7];
  const float* F   = (const float*)d_in[8];

  float* out = (float*)d_out;
  char* ws = (char*)d_ws;
  float*     scattered = (float*)(ws);                  // 12.8 MB
  _Float16*  ABh       = (_Float16*)(ws + 12800000);    // 25.6 MB
  _Float16*  outb      = (_Float16*)(ws + 38400000);    // 6.4 MB
  float*     sums      = (float*)(ws + 44800000);       // 0.4 MB
  int*       row_s     = (int*)(ws + 45200000);         // 6.4 MB
  int*       col_s     = (int*)(ws + 51600000);         // 6.4 MB
  int*       deg       = (int*)(ws + 58000000);         // 0.4 MB
  int*       cur       = (int*)(ws + 58400000);         // 0.4 MB
  int*       bsums     = (int*)(ws + 58800000);         // 4 KB
  _Float16*  WpreT     = (_Float16*)(ws + 58810000);    // 16 KB
  _Float16*  w2pk      = (_Float16*)(ws + 58830000);    // 4 KB
  _Float16*  w1epk     = (_Float16*)(ws + 58840000);    // 4 KB
  _Float16*  ea_s      = (_Float16*)(ws + 58900000);    // 25.6 MB

  dim3 blk(256);
  dim3 grid_e(NE / 256);          // 6250, exact
  dim3 grid_n((NN + 255) / 256);  // 391
  dim3 grid_p((NN + 63) / 64);    // 1563
  int nscan = (NN + 1023) / 1024; // 98

  setup_kernel<<<3125, blk, 0, stream>>>(W1, W2, WpreT, w2pk, w1epk,
                                         (float4*)scattered, deg);
  hist_kernel<<<grid_e, blk, 0, stream>>>(ei, deg);
  scan1_kernel<<<nscan, blk, 0, stream>>>(deg, cur, bsums);
  scan3_kernel<<<grid_n, blk, 0, stream>>>(cur, bsums);
  fill_kernel<<<grid_e, blk, 0, stream>>>(ei, ea, cur, row_s, col_s, ea_s);

  init_kernel<<<grid_n, blk, 0, stream>>>(x_t, F, out, outb, sums);

  for (int k = 0; k < 2; ++k) {
    pre_kernel<<<grid_p, blk, 0, stream>>>(x_s, outb, WpreT, ABh);
    edge_kernel<<<grid_e, blk, 0, stream>>>(ABh, outb, sums, ea_s,
                                            row_s, col_s, b1, b2,
                                            w2pk, w1epk, scattered);
    node_kernel<<<grid_n, blk, 0, stream>>>(out, scattered,
                                            F + (size_t)(k + 1) * DF * DF,
                                            outb, sums);
  }
}

// Round 9
// 451.098 us; speedup vs baseline: 1.3313x; 1.0026x over previous
//
#include <hip/hip_runtime.h>

#define NN 100000
#define NE 1600000
#define SF 16
#define DF 32
#define EFT 8
#define HF 64

typedef __attribute__((ext_vector_type(8))) _Float16 half8;
typedef __attribute__((ext_vector_type(4))) _Float16 half4v;
typedef __attribute__((ext_vector_type(8))) short short8;
typedef __attribute__((ext_vector_type(4))) float floatx4;

// ---------------- CSR build ----------------
__global__ __launch_bounds__(256) void hist_kernel(const int* __restrict__ ei,
                                                   int* __restrict__ deg) {
  int e = blockIdx.x * 256 + threadIdx.x;
  if (e < NE) atomicAdd(&deg[ei[NE + e]], 1);
}

__global__ __launch_bounds__(256) void scan1_kernel(const int* __restrict__ deg,
                                                    int* __restrict__ cur,
                                                    int* __restrict__ bsums) {
  __shared__ int ts[256];
  int tid = threadIdx.x;
  int base = blockIdx.x * 1024 + tid * 4;
  int v[4];
#pragma unroll
  for (int q = 0; q < 4; ++q) v[q] = (base + q < NN) ? deg[base + q] : 0;
  int s = v[0] + v[1] + v[2] + v[3];
  ts[tid] = s;
  __syncthreads();
  for (int off = 1; off < 256; off <<= 1) {
    int t = (tid >= off) ? ts[tid - off] : 0;
    __syncthreads();
    ts[tid] += t;
    __syncthreads();
  }
  int excl = ts[tid] - s;
  if (tid == 255) bsums[blockIdx.x] = ts[255];
  int run = excl;
#pragma unroll
  for (int q = 0; q < 4; ++q) {
    if (base + q < NN) cur[base + q] = run;
    run += v[q];
  }
}

__global__ __launch_bounds__(256) void scan3_kernel(int* __restrict__ cur,
                                                    const int* __restrict__ bsums) {
  int i = blockIdx.x * 256 + threadIdx.x;
  int g = blockIdx.x >> 2;
  int pref = 0;
  for (int q = 0; q < g; ++q) pref += bsums[q];
  if (i < NN) cur[i] += pref;
}

// ---- setup: zero scattered+deg; pack WpreT, W2 frags, W1e^T frags (f16) ----
__global__ __launch_bounds__(256) void setup_kernel(
    const float* __restrict__ W1, const float* __restrict__ W2,
    _Float16* __restrict__ WpreT, _Float16* __restrict__ w2pk,
    _Float16* __restrict__ w1epk,
    float4* __restrict__ scattered4, int* __restrict__ deg) {
  int gid = blockIdx.x * 256 + threadIdx.x;
  if (gid < 800000) {
    float4 z = {0.f, 0.f, 0.f, 0.f};
    scattered4[gid] = z;
  }
  if (gid < NN) deg[gid] = 0;
  if (gid < 128 * 64) {
    int col = gid >> 6, k = gid & 63;
    int j = col & 63;
    bool bh = col >= 64;
    float v = 0.f;
    if (k < 16) v = W1[((bh ? 16 : 0) + k) * HF + j];
    else if (k < 48) v = W1[((bh ? 64 : 32) + (k - 16)) * HF + j];
    WpreT[gid] = (_Float16)v;
  }
  if (gid < 2048) {
    // W2 B-frags: lane holds col = nt*16+lcol, k = kt*32 + kgrp*8 + q
    int lane = gid >> 5, idx = gid & 31;
    int kt = idx >> 4, nt = (idx >> 3) & 1, q = idx & 7;
    int kgrp = (lane >> 4) & 3, lcol = lane & 15;
    w2pk[gid] = (_Float16)W2[(kt * 32 + kgrp * 8 + q) * DF + nt * 16 + lcol];
  } else if (gid < 4096) {
    // W1e^T A-frags: lane<16 holds row j=lane (within jblk), k=t (k>=8 -> 0)
    int id = gid - 2048;  // lane*32 + jblk*8 + t
    int lane = id >> 5, idx = id & 31;
    int jblk = idx >> 3, t = idx & 7;
    float v = (lane < 16) ? W1[(96 + t) * HF + jblk * 16 + lane] : 0.f;
    w1epk[id] = (_Float16)v;
  }
}

// ---- fill: packed 24B sorted records {int r, int c, half ea[8]} ----
__global__ __launch_bounds__(256) void fill_kernel(
    const int* __restrict__ ei, const float* __restrict__ ea,
    int* __restrict__ cur, char* __restrict__ recs) {
  int e = blockIdx.x * 256 + threadIdx.x;
  int r = ei[e];
  int c = ei[NE + e];
  int pos = atomicAdd(&cur[c], 1);
  const float4* p = (const float4*)(ea + (size_t)e * EFT);
  float4 v0 = p[0], v1 = p[1];
  union { _Float16 h[2]; int i; } p01, p23, p45, p67;
  p01.h[0] = (_Float16)v0.x; p01.h[1] = (_Float16)v0.y;
  p23.h[0] = (_Float16)v0.z; p23.h[1] = (_Float16)v0.w;
  p45.h[0] = (_Float16)v1.x; p45.h[1] = (_Float16)v1.y;
  p67.h[0] = (_Float16)v1.z; p67.h[1] = (_Float16)v1.w;
  int2* rp = (int2*)(recs + (size_t)pos * 24);
  int2 a = {r, c};
  int2 b = {p01.i, p23.i};
  int2 d = {p45.i, p67.i};
  rp[0] = a; rp[1] = b; rp[2] = d;
}

// ---------------- init: out = x_t @ F[0]; also outb(f16), sums ----------------
__global__ __launch_bounds__(256) void init_kernel(
    const float* __restrict__ x_t, const float* __restrict__ F0,
    float* __restrict__ out, _Float16* __restrict__ outb,
    float* __restrict__ sums) {
  int n = blockIdx.x * 256 + threadIdx.x;
  if (n >= NN) return;
  float x[DF];
  const float4* xr = reinterpret_cast<const float4*>(x_t + (size_t)n * DF);
#pragma unroll
  for (int q = 0; q < 8; ++q) {
    float4 v = xr[q];
    x[4*q+0]=v.x; x[4*q+1]=v.y; x[4*q+2]=v.z; x[4*q+3]=v.w;
  }
  float4* orow = reinterpret_cast<float4*>(out + (size_t)n * DF);
  _Float16* ob = outb + (size_t)n * DF;
  float s = 0.f;
#pragma unroll
  for (int q = 0; q < 8; ++q) {
    float4 acc = {0.f, 0.f, 0.f, 0.f};
#pragma unroll
    for (int i = 0; i < DF; ++i) {
      float xi = x[i];
      acc.x = fmaf(xi, F0[i*DF + 4*q+0], acc.x);
      acc.y = fmaf(xi, F0[i*DF + 4*q+1], acc.y);
      acc.z = fmaf(xi, F0[i*DF + 4*q+2], acc.z);
      acc.w = fmaf(xi, F0[i*DF + 4*q+3], acc.w);
    }
    orow[q] = acc;
    s += acc.x + acc.y + acc.z + acc.w;
    half4v pk = {(_Float16)acc.x, (_Float16)acc.y, (_Float16)acc.z, (_Float16)acc.w};
    *(half4v*)(ob + 4*q) = pk;
  }
  sums[n] = s;
}

// ------- pre (f16 MFMA): ABh[n][128] = [xs|out|0] @ Wpre -------
__global__ __launch_bounds__(256, 4) void pre_kernel(
    const float* __restrict__ x_s, const _Float16* __restrict__ outb,
    const _Float16* __restrict__ WpreT, _Float16* __restrict__ ABh) {
  __shared__ _Float16 wlds[128][72];
  int tid = threadIdx.x;
  for (int t = tid; t < 1024; t += 256) {
    int colr = t >> 3, kc = t & 7;
    *(half8*)(&wlds[colr][kc * 8]) = *(const half8*)(WpreT + colr * 64 + kc * 8);
  }
  __syncthreads();

  int lcol = tid & 15, kgrp = (tid >> 4) & 3, wid = tid >> 6;
  int nodebase = blockIdx.x * 64 + wid * 16;
  int nodeA = nodebase + lcol;

  half8 a0 = {}, a1 = {};
  if (nodeA < NN) {
    const _Float16* obp = outb + (size_t)nodeA * DF;
    if (kgrp < 2) {
      const float4* p = (const float4*)(x_s + (size_t)nodeA * SF);
      float4 v0 = p[kgrp * 2], v1 = p[kgrp * 2 + 1];
      a0[0]=(_Float16)v0.x; a0[1]=(_Float16)v0.y;
      a0[2]=(_Float16)v0.z; a0[3]=(_Float16)v0.w;
      a0[4]=(_Float16)v1.x; a0[5]=(_Float16)v1.y;
      a0[6]=(_Float16)v1.z; a0[7]=(_Float16)v1.w;
      a1 = *(const half8*)(obp + 16 + kgrp * 8);
    } else if (kgrp == 2) {
      a0 = *(const half8*)(obp + 0);
    } else {
      a0 = *(const half8*)(obp + 8);
    }
  }

  floatx4 acc[8];
#pragma unroll
  for (int nt = 0; nt < 8; ++nt) {
    half8 b0 = *(const half8*)(&wlds[nt * 16 + lcol][kgrp * 8]);
    half8 b1v = *(const half8*)(&wlds[nt * 16 + lcol][32 + kgrp * 8]);
    floatx4 c = {0.f, 0.f, 0.f, 0.f};
    c = __builtin_amdgcn_mfma_f32_16x16x32_f16(a0, b0, c, 0, 0, 0);
    c = __builtin_amdgcn_mfma_f32_16x16x32_f16(a1, b1v, c, 0, 0, 0);
    acc[nt] = c;
  }

#pragma unroll
  for (int rr = 0; rr < 4; ++rr) {
    int node = nodebase + kgrp * 4 + rr;
    if (node < NN) {
      _Float16* dst = ABh + (size_t)node * 128;
#pragma unroll
      for (int nt = 0; nt < 8; ++nt)
        dst[nt * 16 + lcol] = (_Float16)acc[nt][rr];
    }
  }
}

// ---------------- edge MLP (f16 MFMA) + owner-centric epilogue ----------------
__global__ __launch_bounds__(256, 4) void edge_kernel(
    const _Float16* __restrict__ ABh, const _Float16* __restrict__ outb,
    const float* __restrict__ sums, const char* __restrict__ recs,
    const float* __restrict__ b1, const float* __restrict__ b2,
    const _Float16* __restrict__ w2pk, const _Float16* __restrict__ w1epk,
    float* __restrict__ scattered) {
  __shared__ union { _Float16 h[256][72]; float sh[9472]; } u;  // 37,888 B
  __shared__ int scol[256];
  __shared__ unsigned short l0[256], l1[256];
  __shared__ int wbase[4];
  __shared__ int cnt;

  int tid = threadIdx.x;
  int bbase = blockIdx.x * 256;
  int i = bbase + tid;  // NE % 256 == 0: always valid
  if (tid == 0) cnt = 0;
  int lcol = tid & 15, kgrp = (tid >> 4) & 3, wid = tid >> 6;
  int lane = tid & 63;

  // load packed record {r, c, ea[8] f16}
  const int2* rp = (const int2*)(recs + (size_t)i * 24);
  int2 ra = rp[0], rb = rp[1], rd = rp[2];
  int r = ra.x;
  int c = ra.y;
  int4 eai = {rb.x, rb.y, rd.x, rd.y};
  scol[tid] = c;
  float s_r = sums[r], s_c = sums[c];

  const _Float16* wpp = w2pk + (size_t)lane * 32;
  half8 w2f00 = *(const half8*)(wpp);
  half8 w2f01 = *(const half8*)(wpp + 8);
  half8 w2f10 = *(const half8*)(wpp + 16);
  half8 w2f11 = *(const half8*)(wpp + 24);
  float b2c0 = b2[lcol], b2c1 = b2[16 + lcol];

  // ---- phase 0: eaw^T = W1e^T @ ea via swapped MFMA -> packed half4 writes ----
  const _Float16* wep = w1epk + (size_t)lane * 32;
  half8 wA0 = *(const half8*)(wep);
  half8 wA1 = *(const half8*)(wep + 8);
  half8 wA2 = *(const half8*)(wep + 16);
  half8 wA3 = *(const half8*)(wep + 24);
  const float4* b1f4 = (const float4*)b1;
  float4 b1q0 = b1f4[0 + kgrp];
  float4 b1q1 = b1f4[4 + kgrp];
  float4 b1q2 = b1f4[8 + kgrp];
  float4 b1q3 = b1f4[12 + kgrp];
  bool lo16 = lane < 16;
#pragma unroll
  for (int g = 0; g < 4; ++g) {
    int src = g * 16 + lcol;
    int4 t;
    t.x = __shfl(eai.x, src, 64);
    t.y = __shfl(eai.y, src, 64);
    t.z = __shfl(eai.z, src, 64);
    t.w = __shfl(eai.w, src, 64);
    half8 zz = {};
    half8 bg = lo16 ? __builtin_bit_cast(half8, t) : zz;
    int erow = wid * 64 + g * 16 + lcol;
    _Float16* hrow = &u.h[erow][kgrp * 4];
    {
      floatx4 cc = {b1q0.x, b1q0.y, b1q0.z, b1q0.w};
      cc = __builtin_amdgcn_mfma_f32_16x16x32_f16(wA0, bg, cc, 0, 0, 0);
      half4v h4 = {(_Float16)cc[0], (_Float16)cc[1], (_Float16)cc[2], (_Float16)cc[3]};
      *(half4v*)(hrow + 0) = h4;
    }
    {
      floatx4 cc = {b1q1.x, b1q1.y, b1q1.z, b1q1.w};
      cc = __builtin_amdgcn_mfma_f32_16x16x32_f16(wA1, bg, cc, 0, 0, 0);
      half4v h4 = {(_Float16)cc[0], (_Float16)cc[1], (_Float16)cc[2], (_Float16)cc[3]};
      *(half4v*)(hrow + 16) = h4;
    }
    {
      floatx4 cc = {b1q2.x, b1q2.y, b1q2.z, b1q2.w};
      cc = __builtin_amdgcn_mfma_f32_16x16x32_f16(wA2, bg, cc, 0, 0, 0);
      half4v h4 = {(_Float16)cc[0], (_Float16)cc[1], (_Float16)cc[2], (_Float16)cc[3]};
      *(half4v*)(hrow + 32) = h4;
    }
    {
      floatx4 cc = {b1q3.x, b1q3.y, b1q3.z, b1q3.w};
      cc = __builtin_amdgcn_mfma_f32_16x16x32_f16(wA3, bg, cc, 0, 0, 0);
      half4v h4 = {(_Float16)cc[0], (_Float16)cc[1], (_Float16)cc[2], (_Float16)cc[3]};
      *(half4v*)(hrow + 48) = h4;
    }
  }
  // phases 0-2 touch only this wave's h rows (144B stride): wave-local, no barrier

  // ---- phase 1: h = relu(A[r] + B[c] + eaw) packed f16, RMW on u.h[tid] ----
  const _Float16* ar = ABh + (size_t)r * 128;
  const _Float16* bc = ABh + (size_t)c * 128 + 64;
#pragma unroll 4
  for (int q = 0; q < 8; ++q) {
    half8 a = *(const half8*)(ar + q * 8);
    half8 b = *(const half8*)(bc + q * 8);
    half8 w = *(const half8*)(&u.h[tid][q * 8]);
    half8 s = a + b + w;
    short8 sb = __builtin_bit_cast(short8, s);
    short8 m = sb >> 15;
    sb = sb & ~m;  // relu: zero negatives (and -0)
    *(short8*)(&u.h[tid][q * 8]) = sb;
  }

  // ---- phase 2: layer-2 MFMA, 4 groups of 16 edges per wave ----
  floatx4 acc[4][2];
#pragma unroll
  for (int g = 0; g < 4; ++g) {
    int erow = wid * 64 + g * 16 + lcol;
    half8 a0 = *(const half8*)(&u.h[erow][kgrp * 8]);
    half8 a1 = *(const half8*)(&u.h[erow][32 + kgrp * 8]);
    floatx4 c0 = {b2c0, b2c0, b2c0, b2c0};
    floatx4 c1 = {b2c1, b2c1, b2c1, b2c1};
    c0 = __builtin_amdgcn_mfma_f32_16x16x32_f16(a0, w2f00, c0, 0, 0, 0);
    c0 = __builtin_amdgcn_mfma_f32_16x16x32_f16(a1, w2f10, c0, 0, 0, 0);
    c1 = __builtin_amdgcn_mfma_f32_16x16x32_f16(a0, w2f01, c1, 0, 0, 0);
    c1 = __builtin_amdgcn_mfma_f32_16x16x32_f16(a1, w2f11, c1, 0, 0, 0);
    acc[g][0] = c0;
    acc[g][1] = c1;
  }

  // RACE FIX (round-8 NaN): u.sh rows are 148B-stride vs u.h 144B-stride, so
  // wave w's sh region [w*9472, w*9472+9472) overlaps wave w+1's h rows
  // starting at (w+1)*9216. All waves must finish their phase-2 h reads
  // before ANY wave writes sh.
  __syncthreads();

  // ---- phase 3a: dump o (C-frags) to LDS, stride-37 f32 rows ----
#pragma unroll
  for (int g = 0; g < 4; ++g) {
#pragma unroll
    for (int rr = 0; rr < 4; ++rr) {
      int e = wid * 64 + g * 16 + kgrp * 4 + rr;
      u.sh[e * 37 + lcol]      = acc[g][0][rr];
      u.sh[e * 37 + 16 + lcol] = acc[g][1][rr];
    }
  }

  // ---- phase 3b: owner-centric norm + mask + shift (all wave-local) ----
  {
    float o2[32];
    float nsq = 0.f;
#pragma unroll
    for (int j = 0; j < 32; ++j) {
      float v = u.sh[tid * 37 + j];
      o2[j] = v;
      nsq = fmaf(v, v, nsq);
    }
    float ms = (nsq > 0.f) ? rsqrtf(nsq) : 0.f;
    if (s_r == 0.f && s_c == 0.f) ms = 0.f;
    const half8* orp = (const half8*)(outb + (size_t)r * DF);
    const half8* ocp = (const half8*)(outb + (size_t)c * DF);
#pragma unroll
    for (int q = 0; q < 4; ++q) {
      half8 av = orp[q], bv = ocp[q];
#pragma unroll
      for (int jj = 0; jj < 8; ++jj)
        u.sh[tid * 37 + q * 8 + jj] =
            ((float)bv[jj] - (float)av[jj]) * o2[q * 8 + jj] * ms;
    }
  }
  __syncthreads();  // cross-wave: sh rows + scol + cnt now visible

  // ---- phase 4: segmented reduce over sorted-col runs ----
  int c_self = scol[tid];
  bool head = (tid == 0 || scol[tid - 1] != c_self);
  unsigned long long m = __ballot(head);
  if (lane == 0) wbase[wid] = atomicAdd(&cnt, (int)__popcll(m));
  __syncthreads();
  if (head) {
    int idx = wbase[wid] + (int)__popcll(m & ((1ull << lane) - 1ull));
    int t1 = tid + 1;
    while (t1 < 256 && scol[t1] == c_self) ++t1;
    l0[idx] = (unsigned short)tid;
    l1[idx] = (unsigned short)t1;
  }
  __syncthreads();
  int nr = cnt;
  for (int task = tid; task < nr * 32; task += 256) {
    int rid = task >> 5, j = task & 31;
    int t0 = l0[rid], t1 = l1[rid];
    float s = 0.f;
    for (int t = t0; t < t1; ++t) s += u.sh[t * 37 + j];
    unsafeAtomicAdd(&scattered[(size_t)scol[t0] * DF + j], s);
  }
}

// --- node update (in place): out += scattered @ Fk; outb/sums; clear sc ---
__global__ __launch_bounds__(256) void node_kernel(
    float* __restrict__ out, float* __restrict__ scattered,
    const float* __restrict__ Fk, _Float16* __restrict__ outb,
    float* __restrict__ sums) {
  int n = blockIdx.x * 256 + threadIdx.x;
  if (n >= NN) return;
  float s[DF];
  float4* sp = reinterpret_cast<float4*>(scattered + (size_t)n * DF);
#pragma unroll
  for (int q = 0; q < 8; ++q) {
    float4 v = sp[q];
    s[4*q+0]=v.x; s[4*q+1]=v.y; s[4*q+2]=v.z; s[4*q+3]=v.w;
  }
  float4* op = reinterpret_cast<float4*>(out + (size_t)n * DF);
  _Float16* ob = outb + (size_t)n * DF;
  float ssum = 0.f;
#pragma unroll
  for (int q = 0; q < 8; ++q) {
    float4 acc = op[q];
#pragma unroll
    for (int i = 0; i < DF; ++i) {
      float si = s[i];
      acc.x = fmaf(si, Fk[i*DF + 4*q+0], acc.x);
      acc.y = fmaf(si, Fk[i*DF + 4*q+1], acc.y);
      acc.z = fmaf(si, Fk[i*DF + 4*q+2], acc.z);
      acc.w = fmaf(si, Fk[i*DF + 4*q+3], acc.w);
    }
    op[q] = acc;
    ssum += acc.x + acc.y + acc.z + acc.w;
    half4v pk = {(_Float16)acc.x, (_Float16)acc.y, (_Float16)acc.z, (_Float16)acc.w};
    *(half4v*)(ob + 4*q) = pk;
  }
  sums[n] = ssum;
  float4 z = {0.f, 0.f, 0.f, 0.f};
#pragma unroll
  for (int q = 0; q < 8; ++q) sp[q] = z;
}

extern "C" void kernel_launch(void* const* d_in, const int* in_sizes, int n_in,
                              void* d_out, int out_size, void* d_ws, size_t ws_size,
                              hipStream_t stream) {
  const float* x_s = (const float*)d_in[0];
  const float* x_t = (const float*)d_in[1];
  const int*   ei  = (const int*)d_in[2];
  const float* ea  = (const float*)d_in[3];
  const float* W1  = (const float*)d_in[4];
  const float* b1  = (const float*)d_in[5];
  const float* W2  = (const float*)d_in[6];
  const float* b2  = (const float*)d_in[7];
  const float* F   = (const float*)d_in[8];

  float* out = (float*)d_out;
  char* ws = (char*)d_ws;
  float*     scattered = (float*)(ws);                  // 12.8 MB
  _Float16*  ABh       = (_Float16*)(ws + 12800000);    // 25.6 MB
  _Float16*  outb      = (_Float16*)(ws + 38400000);    // 6.4 MB
  float*     sums      = (float*)(ws + 44800000);       // 0.4 MB
  char*      recs      = (char*)(ws + 45200000);        // 38.4 MB (24B/edge)
  int*       deg       = (int*)(ws + 83600000);         // 0.4 MB
  int*       cur       = (int*)(ws + 84000000);         // 0.4 MB
  int*       bsums     = (int*)(ws + 84400000);         // 4 KB
  _Float16*  WpreT     = (_Float16*)(ws + 84410000);    // 16 KB
  _Float16*  w2pk      = (_Float16*)(ws + 84430000);    // 4 KB
  _Float16*  w1epk     = (_Float16*)(ws + 84440000);    // 4 KB

  dim3 blk(256);
  dim3 grid_e(NE / 256);          // 6250, exact
  dim3 grid_n((NN + 255) / 256);  // 391
  dim3 grid_p((NN + 63) / 64);    // 1563
  int nscan = (NN + 1023) / 1024; // 98

  setup_kernel<<<3125, blk, 0, stream>>>(W1, W2, WpreT, w2pk, w1epk,
                                         (float4*)scattered, deg);
  hist_kernel<<<grid_e, blk, 0, stream>>>(ei, deg);
  scan1_kernel<<<nscan, blk, 0, stream>>>(deg, cur, bsums);
  scan3_kernel<<<grid_n, blk, 0, stream>>>(cur, bsums);
  fill_kernel<<<grid_e, blk, 0, stream>>>(ei, ea, cur, recs);

  init_kernel<<<grid_n, blk, 0, stream>>>(x_t, F, out, outb, sums);

  for (int k = 0; k < 2; ++k) {
    pre_kernel<<<grid_p, blk, 0, stream>>>(x_s, outb, WpreT, ABh);
    edge_kernel<<<grid_e, blk, 0, stream>>>(ABh, outb, sums, recs, b1, b2,
                                            w2pk, w1epk, scattered);
    node_kernel<<<grid_n, blk, 0, stream>>>(out, scattered,
                                            F + (size_t)(k + 1) * DF * DF,
                                            outb, sums);
  }
}

// Round 10
// 441.667 us; speedup vs baseline: 1.3598x; 1.0214x over previous
//
#include <hip/hip_runtime.h>

#define NN 100000
#define NE 1600000
#define SF 16
#define DF 32
#define EFT 8
#define HF 64

typedef __attribute__((ext_vector_type(8))) _Float16 half8;
typedef __attribute__((ext_vector_type(4))) _Float16 half4v;
typedef __attribute__((ext_vector_type(8))) short short8;
typedef __attribute__((ext_vector_type(4))) float floatx4;

// swizzled half-index into the [256][64] h tile (128B rows, 16B-granule XOR)
__device__ inline int hswz(int row, int halfoff) {
  int gran = halfoff >> 3, sub = halfoff & 7;
  return row * 64 + ((gran ^ (row & 7)) << 3) + sub;
}

// ---------------- CSR build ----------------
__global__ __launch_bounds__(256) void hist_kernel(const int* __restrict__ ei,
                                                   int* __restrict__ deg) {
  int e = blockIdx.x * 256 + threadIdx.x;
  if (e < NE) atomicAdd(&deg[ei[NE + e]], 1);
}

__global__ __launch_bounds__(256) void scan1_kernel(const int* __restrict__ deg,
                                                    int* __restrict__ cur,
                                                    int* __restrict__ bsums) {
  __shared__ int ts[256];
  int tid = threadIdx.x;
  int base = blockIdx.x * 1024 + tid * 4;
  int v[4];
#pragma unroll
  for (int q = 0; q < 4; ++q) v[q] = (base + q < NN) ? deg[base + q] : 0;
  int s = v[0] + v[1] + v[2] + v[3];
  ts[tid] = s;
  __syncthreads();
  for (int off = 1; off < 256; off <<= 1) {
    int t = (tid >= off) ? ts[tid - off] : 0;
    __syncthreads();
    ts[tid] += t;
    __syncthreads();
  }
  int excl = ts[tid] - s;
  if (tid == 255) bsums[blockIdx.x] = ts[255];
  int run = excl;
#pragma unroll
  for (int q = 0; q < 4; ++q) {
    if (base + q < NN) cur[base + q] = run;
    run += v[q];
  }
}

__global__ __launch_bounds__(256) void scan3_kernel(int* __restrict__ cur,
                                                    const int* __restrict__ bsums) {
  int i = blockIdx.x * 256 + threadIdx.x;
  int g = blockIdx.x >> 2;
  int pref = 0;
  for (int q = 0; q < g; ++q) pref += bsums[q];
  if (i < NN) cur[i] += pref;
}

// ---- setup: zero scattered+deg; pack WpreT, W2 frags, W1e^T frags (f16) ----
__global__ __launch_bounds__(256) void setup_kernel(
    const float* __restrict__ W1, const float* __restrict__ W2,
    _Float16* __restrict__ WpreT, _Float16* __restrict__ w2pk,
    _Float16* __restrict__ w1epk,
    float4* __restrict__ scattered4, int* __restrict__ deg) {
  int gid = blockIdx.x * 256 + threadIdx.x;
  if (gid < 800000) {
    float4 z = {0.f, 0.f, 0.f, 0.f};
    scattered4[gid] = z;
  }
  if (gid < NN) deg[gid] = 0;
  if (gid < 128 * 64) {
    int col = gid >> 6, k = gid & 63;
    int j = col & 63;
    bool bh = col >= 64;
    float v = 0.f;
    if (k < 16) v = W1[((bh ? 16 : 0) + k) * HF + j];
    else if (k < 48) v = W1[((bh ? 64 : 32) + (k - 16)) * HF + j];
    WpreT[gid] = (_Float16)v;
  }
  if (gid < 2048) {
    // W2 B-frags: lane holds col = nt*16+lcol, k = kt*32 + kgrp*8 + q
    int lane = gid >> 5, idx = gid & 31;
    int kt = idx >> 4, nt = (idx >> 3) & 1, q = idx & 7;
    int kgrp = (lane >> 4) & 3, lcol = lane & 15;
    w2pk[gid] = (_Float16)W2[(kt * 32 + kgrp * 8 + q) * DF + nt * 16 + lcol];
  } else if (gid < 4096) {
    // W1e^T A-frags: lane<16 holds row j=lane (within jblk), k=t (k>=8 -> 0)
    int id = gid - 2048;  // lane*32 + jblk*8 + t
    int lane = id >> 5, idx = id & 31;
    int jblk = idx >> 3, t = idx & 7;
    float v = (lane < 16) ? W1[(96 + t) * HF + jblk * 16 + lane] : 0.f;
    w1epk[id] = (_Float16)v;
  }
}

// ---- fill: packed 24B sorted records {int r, int c, half ea[8]} ----
__global__ __launch_bounds__(256) void fill_kernel(
    const int* __restrict__ ei, const float* __restrict__ ea,
    int* __restrict__ cur, char* __restrict__ recs) {
  int e = blockIdx.x * 256 + threadIdx.x;
  int r = ei[e];
  int c = ei[NE + e];
  int pos = atomicAdd(&cur[c], 1);
  const float4* p = (const float4*)(ea + (size_t)e * EFT);
  float4 v0 = p[0], v1 = p[1];
  union { _Float16 h[2]; int i; } p01, p23, p45, p67;
  p01.h[0] = (_Float16)v0.x; p01.h[1] = (_Float16)v0.y;
  p23.h[0] = (_Float16)v0.z; p23.h[1] = (_Float16)v0.w;
  p45.h[0] = (_Float16)v1.x; p45.h[1] = (_Float16)v1.y;
  p67.h[0] = (_Float16)v1.z; p67.h[1] = (_Float16)v1.w;
  int2* rp = (int2*)(recs + (size_t)pos * 24);
  int2 a = {r, c};
  int2 b = {p01.i, p23.i};
  int2 d = {p45.i, p67.i};
  rp[0] = a; rp[1] = b; rp[2] = d;
}

// ---------------- init: out = x_t @ F[0]; also outb(f16), sums ----------------
__global__ __launch_bounds__(256) void init_kernel(
    const float* __restrict__ x_t, const float* __restrict__ F0,
    float* __restrict__ out, _Float16* __restrict__ outb,
    float* __restrict__ sums) {
  int n = blockIdx.x * 256 + threadIdx.x;
  if (n >= NN) return;
  float x[DF];
  const float4* xr = reinterpret_cast<const float4*>(x_t + (size_t)n * DF);
#pragma unroll
  for (int q = 0; q < 8; ++q) {
    float4 v = xr[q];
    x[4*q+0]=v.x; x[4*q+1]=v.y; x[4*q+2]=v.z; x[4*q+3]=v.w;
  }
  float4* orow = reinterpret_cast<float4*>(out + (size_t)n * DF);
  _Float16* ob = outb + (size_t)n * DF;
  float s = 0.f;
#pragma unroll
  for (int q = 0; q < 8; ++q) {
    float4 acc = {0.f, 0.f, 0.f, 0.f};
#pragma unroll
    for (int i = 0; i < DF; ++i) {
      float xi = x[i];
      acc.x = fmaf(xi, F0[i*DF + 4*q+0], acc.x);
      acc.y = fmaf(xi, F0[i*DF + 4*q+1], acc.y);
      acc.z = fmaf(xi, F0[i*DF + 4*q+2], acc.z);
      acc.w = fmaf(xi, F0[i*DF + 4*q+3], acc.w);
    }
    orow[q] = acc;
    s += acc.x + acc.y + acc.z + acc.w;
    half4v pk = {(_Float16)acc.x, (_Float16)acc.y, (_Float16)acc.z, (_Float16)acc.w};
    *(half4v*)(ob + 4*q) = pk;
  }
  sums[n] = s;
}

// ------- pre (f16 MFMA): ABh[n][128] = [xs|out|0] @ Wpre -------
__global__ __launch_bounds__(256, 4) void pre_kernel(
    const float* __restrict__ x_s, const _Float16* __restrict__ outb,
    const _Float16* __restrict__ WpreT, _Float16* __restrict__ ABh) {
  __shared__ _Float16 wlds[128][72];
  int tid = threadIdx.x;
  for (int t = tid; t < 1024; t += 256) {
    int colr = t >> 3, kc = t & 7;
    *(half8*)(&wlds[colr][kc * 8]) = *(const half8*)(WpreT + colr * 64 + kc * 8);
  }
  __syncthreads();

  int lcol = tid & 15, kgrp = (tid >> 4) & 3, wid = tid >> 6;
  int nodebase = blockIdx.x * 64 + wid * 16;
  int nodeA = nodebase + lcol;

  half8 a0 = {}, a1 = {};
  if (nodeA < NN) {
    const _Float16* obp = outb + (size_t)nodeA * DF;
    if (kgrp < 2) {
      const float4* p = (const float4*)(x_s + (size_t)nodeA * SF);
      float4 v0 = p[kgrp * 2], v1 = p[kgrp * 2 + 1];
      a0[0]=(_Float16)v0.x; a0[1]=(_Float16)v0.y;
      a0[2]=(_Float16)v0.z; a0[3]=(_Float16)v0.w;
      a0[4]=(_Float16)v1.x; a0[5]=(_Float16)v1.y;
      a0[6]=(_Float16)v1.z; a0[7]=(_Float16)v1.w;
      a1 = *(const half8*)(obp + 16 + kgrp * 8);
    } else if (kgrp == 2) {
      a0 = *(const half8*)(obp + 0);
    } else {
      a0 = *(const half8*)(obp + 8);
    }
  }

  floatx4 acc[8];
#pragma unroll
  for (int nt = 0; nt < 8; ++nt) {
    half8 b0 = *(const half8*)(&wlds[nt * 16 + lcol][kgrp * 8]);
    half8 b1v = *(const half8*)(&wlds[nt * 16 + lcol][32 + kgrp * 8]);
    floatx4 c = {0.f, 0.f, 0.f, 0.f};
    c = __builtin_amdgcn_mfma_f32_16x16x32_f16(a0, b0, c, 0, 0, 0);
    c = __builtin_amdgcn_mfma_f32_16x16x32_f16(a1, b1v, c, 0, 0, 0);
    acc[nt] = c;
  }

#pragma unroll
  for (int rr = 0; rr < 4; ++rr) {
    int node = nodebase + kgrp * 4 + rr;
    if (node < NN) {
      _Float16* dst = ABh + (size_t)node * 128;
#pragma unroll
      for (int nt = 0; nt < 8; ++nt)
        dst[nt * 16 + lcol] = (_Float16)acc[nt][rr];
    }
  }
}

// ---------------- edge MLP (f16 MFMA) + owner-centric epilogue ----------------
__global__ __launch_bounds__(256, 4) void edge_kernel(
    const _Float16* __restrict__ ABh, const _Float16* __restrict__ outb,
    const float* __restrict__ sums, const char* __restrict__ recs,
    const float* __restrict__ b1, const float* __restrict__ b2,
    const _Float16* __restrict__ w2pk, const _Float16* __restrict__ w1epk,
    float* __restrict__ scattered) {
  // h: [256][64] halves, 128B rows, XOR-swizzled granules (32768 B)
  // sh: [256] rows of 33 f32 (33792 B) -> union 33792 B
  __shared__ union { _Float16 h[256 * 64]; float sh[256 * 33]; } u;
  __shared__ int scol[256];
  __shared__ unsigned short l0[256], l1[256];
  __shared__ int wbase[4];
  __shared__ int cnt;

  int tid = threadIdx.x;
  int bbase = blockIdx.x * 256;
  int i = bbase + tid;  // NE % 256 == 0: always valid
  if (tid == 0) cnt = 0;
  int lcol = tid & 15, kgrp = (tid >> 4) & 3, wid = tid >> 6;
  int lane = tid & 63;

  // load packed record {r, c, ea[8] f16}
  const int2* rp = (const int2*)(recs + (size_t)i * 24);
  int2 ra = rp[0], rb = rp[1], rd = rp[2];
  int r = ra.x;
  int c = ra.y;
  int4 eai = {rb.x, rb.y, rd.x, rd.y};
  scol[tid] = c;
  float s_r = sums[r], s_c = sums[c];

  // EARLY-ISSUE: stage A[r] and B[c] halves (128B each) into registers so
  // the HBM/L3 latency hides under phase-0's shuffles + MFMAs.
  half8 Ar[8], Bc[8];
  {
    const half8* arp = (const half8*)(ABh + (size_t)r * 128);
    const half8* bcp = (const half8*)(ABh + (size_t)c * 128 + 64);
#pragma unroll
    for (int q = 0; q < 8; ++q) { Ar[q] = arp[q]; Bc[q] = bcp[q]; }
  }

  float b2c0 = b2[lcol], b2c1 = b2[16 + lcol];

  // ---- phase 0: eaw^T = W1e^T @ ea via swapped MFMA -> swizzled half4 writes ----
  const _Float16* wep = w1epk + (size_t)lane * 32;
  half8 wA0 = *(const half8*)(wep);
  half8 wA1 = *(const half8*)(wep + 8);
  half8 wA2 = *(const half8*)(wep + 16);
  half8 wA3 = *(const half8*)(wep + 24);
  const float4* b1f4 = (const float4*)b1;
  float4 b1q0 = b1f4[0 + kgrp];
  float4 b1q1 = b1f4[4 + kgrp];
  float4 b1q2 = b1f4[8 + kgrp];
  float4 b1q3 = b1f4[12 + kgrp];
  bool lo16 = lane < 16;
#pragma unroll
  for (int g = 0; g < 4; ++g) {
    int src = g * 16 + lcol;
    int4 t;
    t.x = __shfl(eai.x, src, 64);
    t.y = __shfl(eai.y, src, 64);
    t.z = __shfl(eai.z, src, 64);
    t.w = __shfl(eai.w, src, 64);
    half8 zz = {};
    half8 bg = lo16 ? __builtin_bit_cast(half8, t) : zz;
    int erow = wid * 64 + g * 16 + lcol;
    {
      floatx4 cc = {b1q0.x, b1q0.y, b1q0.z, b1q0.w};
      cc = __builtin_amdgcn_mfma_f32_16x16x32_f16(wA0, bg, cc, 0, 0, 0);
      half4v h4 = {(_Float16)cc[0], (_Float16)cc[1], (_Float16)cc[2], (_Float16)cc[3]};
      *(half4v*)(&u.h[hswz(erow, 0 * 16 + kgrp * 4)]) = h4;
    }
    {
      floatx4 cc = {b1q1.x, b1q1.y, b1q1.z, b1q1.w};
      cc = __builtin_amdgcn_mfma_f32_16x16x32_f16(wA1, bg, cc, 0, 0, 0);
      half4v h4 = {(_Float16)cc[0], (_Float16)cc[1], (_Float16)cc[2], (_Float16)cc[3]};
      *(half4v*)(&u.h[hswz(erow, 1 * 16 + kgrp * 4)]) = h4;
    }
    {
      floatx4 cc = {b1q2.x, b1q2.y, b1q2.z, b1q2.w};
      cc = __builtin_amdgcn_mfma_f32_16x16x32_f16(wA2, bg, cc, 0, 0, 0);
      half4v h4 = {(_Float16)cc[0], (_Float16)cc[1], (_Float16)cc[2], (_Float16)cc[3]};
      *(half4v*)(&u.h[hswz(erow, 2 * 16 + kgrp * 4)]) = h4;
    }
    {
      floatx4 cc = {b1q3.x, b1q3.y, b1q3.z, b1q3.w};
      cc = __builtin_amdgcn_mfma_f32_16x16x32_f16(wA3, bg, cc, 0, 0, 0);
      half4v h4 = {(_Float16)cc[0], (_Float16)cc[1], (_Float16)cc[2], (_Float16)cc[3]};
      *(half4v*)(&u.h[hswz(erow, 3 * 16 + kgrp * 4)]) = h4;
    }
  }
  // phases 0-2 touch only this wave's h rows: wave-local, no block barrier

  // ---- phase 1: h = relu(A[r] + B[c] + eaw) packed f16, RMW on own row ----
#pragma unroll
  for (int q = 0; q < 8; ++q) {
    int idx = hswz(tid, q * 8);
    half8 w = *(const half8*)(&u.h[idx]);
    half8 s = Ar[q] + Bc[q] + w;
    short8 sb = __builtin_bit_cast(short8, s);
    short8 m = sb >> 15;
    sb = sb & ~m;  // relu: zero negatives (and -0)
    *(short8*)(&u.h[idx]) = sb;
  }

  // ---- phase 2: layer-2 MFMA, 4 groups of 16 edges per wave ----
  const _Float16* wpp = w2pk + (size_t)lane * 32;
  half8 w2f00 = *(const half8*)(wpp);
  half8 w2f01 = *(const half8*)(wpp + 8);
  half8 w2f10 = *(const half8*)(wpp + 16);
  half8 w2f11 = *(const half8*)(wpp + 24);
  floatx4 acc[4][2];
#pragma unroll
  for (int g = 0; g < 4; ++g) {
    int erow = wid * 64 + g * 16 + lcol;
    half8 a0 = *(const half8*)(&u.h[hswz(erow, kgrp * 8)]);
    half8 a1 = *(const half8*)(&u.h[hswz(erow, 32 + kgrp * 8)]);
    floatx4 c0 = {b2c0, b2c0, b2c0, b2c0};
    floatx4 c1 = {b2c1, b2c1, b2c1, b2c1};
    c0 = __builtin_amdgcn_mfma_f32_16x16x32_f16(a0, w2f00, c0, 0, 0, 0);
    c0 = __builtin_amdgcn_mfma_f32_16x16x32_f16(a1, w2f10, c0, 0, 0, 0);
    c1 = __builtin_amdgcn_mfma_f32_16x16x32_f16(a0, w2f01, c1, 0, 0, 0);
    c1 = __builtin_amdgcn_mfma_f32_16x16x32_f16(a1, w2f11, c1, 0, 0, 0);
    acc[g][0] = c0;
    acc[g][1] = c1;
  }

  // EARLY-ISSUE: outb rows for the epilogue, overlapping the barrier wait.
  half8 Or[4], Oc[4];
  {
    const half8* orp = (const half8*)(outb + (size_t)r * DF);
    const half8* ocp = (const half8*)(outb + (size_t)c * DF);
#pragma unroll
    for (int q = 0; q < 4; ++q) { Or[q] = orp[q]; Oc[q] = ocp[q]; }
  }

  // RACE FIX: all waves must finish phase-2 h reads before any sh writes
  // (the two union views have different row strides -> cross-wave overlap).
  __syncthreads();

  // ---- phase 3a: dump o (C-frags) to LDS, stride-33 f32 rows ----
#pragma unroll
  for (int g = 0; g < 4; ++g) {
#pragma unroll
    for (int rr = 0; rr < 4; ++rr) {
      int e = wid * 64 + g * 16 + kgrp * 4 + rr;
      u.sh[e * 33 + lcol]      = acc[g][0][rr];
      u.sh[e * 33 + 16 + lcol] = acc[g][1][rr];
    }
  }

  // ---- phase 3b: owner-centric norm + mask + shift (all wave-local) ----
  {
    float o2[32];
    float nsq = 0.f;
#pragma unroll
    for (int j = 0; j < 32; ++j) {
      float v = u.sh[tid * 33 + j];
      o2[j] = v;
      nsq = fmaf(v, v, nsq);
    }
    float ms = (nsq > 0.f) ? rsqrtf(nsq) : 0.f;
    if (s_r == 0.f && s_c == 0.f) ms = 0.f;
#pragma unroll
    for (int q = 0; q < 4; ++q) {
#pragma unroll
      for (int jj = 0; jj < 8; ++jj)
        u.sh[tid * 33 + q * 8 + jj] =
            ((float)Oc[q][jj] - (float)Or[q][jj]) * o2[q * 8 + jj] * ms;
    }
  }
  __syncthreads();  // cross-wave: sh rows + scol + cnt now visible

  // ---- phase 4: segmented reduce over sorted-col runs ----
  int c_self = scol[tid];
  bool head = (tid == 0 || scol[tid - 1] != c_self);
  unsigned long long m = __ballot(head);
  if (lane == 0) wbase[wid] = atomicAdd(&cnt, (int)__popcll(m));
  __syncthreads();
  if (head) {
    int idx = wbase[wid] + (int)__popcll(m & ((1ull << lane) - 1ull));
    int t1 = tid + 1;
    while (t1 < 256 && scol[t1] == c_self) ++t1;
    l0[idx] = (unsigned short)tid;
    l1[idx] = (unsigned short)t1;
  }
  __syncthreads();
  int nr = cnt;
  for (int task = tid; task < nr * 32; task += 256) {
    int rid = task >> 5, j = task & 31;
    int t0 = l0[rid], t1 = l1[rid];
    float s = 0.f;
    for (int t = t0; t < t1; ++t) s += u.sh[t * 33 + j];
    unsafeAtomicAdd(&scattered[(size_t)scol[t0] * DF + j], s);
  }
}

// --- node update (in place): out += scattered @ Fk; outb/sums; clear sc ---
__global__ __launch_bounds__(256) void node_kernel(
    float* __restrict__ out, float* __restrict__ scattered,
    const float* __restrict__ Fk, _Float16* __restrict__ outb,
    float* __restrict__ sums) {
  int n = blockIdx.x * 256 + threadIdx.x;
  if (n >= NN) return;
  float s[DF];
  float4* sp = reinterpret_cast<float4*>(scattered + (size_t)n * DF);
#pragma unroll
  for (int q = 0; q < 8; ++q) {
    float4 v = sp[q];
    s[4*q+0]=v.x; s[4*q+1]=v.y; s[4*q+2]=v.z; s[4*q+3]=v.w;
  }
  float4* op = reinterpret_cast<float4*>(out + (size_t)n * DF);
  _Float16* ob = outb + (size_t)n * DF;
  float ssum = 0.f;
#pragma unroll
  for (int q = 0; q < 8; ++q) {
    float4 acc = op[q];
#pragma unroll
    for (int i = 0; i < DF; ++i) {
      float si = s[i];
      acc.x = fmaf(si, Fk[i*DF + 4*q+0], acc.x);
      acc.y = fmaf(si, Fk[i*DF + 4*q+1], acc.y);
      acc.z = fmaf(si, Fk[i*DF + 4*q+2], acc.z);
      acc.w = fmaf(si, Fk[i*DF + 4*q+3], acc.w);
    }
    op[q] = acc;
    ssum += acc.x + acc.y + acc.z + acc.w;
    half4v pk = {(_Float16)acc.x, (_Float16)acc.y, (_Float16)acc.z, (_Float16)acc.w};
    *(half4v*)(ob + 4*q) = pk;
  }
  sums[n] = ssum;
  float4 z = {0.f, 0.f, 0.f, 0.f};
#pragma unroll
  for (int q = 0; q < 8; ++q) sp[q] = z;
}

extern "C" void kernel_launch(void* const* d_in, const int* in_sizes, int n_in,
                              void* d_out, int out_size, void* d_ws, size_t ws_size,
                              hipStream_t stream) {
  const float* x_s = (const float*)d_in[0];
  const float* x_t = (const float*)d_in[1];
  const int*   ei  = (const int*)d_in[2];
  const float* ea  = (const float*)d_in[3];
  const float* W1  = (const float*)d_in[4];
  const float* b1  = (const float*)d_in[5];
  const float* W2  = (const float*)d_in[6];
  const float* b2  = (const float*)d_in[7];
  const float* F   = (const float*)d_in[8];

  float* out = (float*)d_out;
  char* ws = (char*)d_ws;
  float*     scattered = (float*)(ws);                  // 12.8 MB
  _Float16*  ABh       = (_Float16*)(ws + 12800000);    // 25.6 MB
  _Float16*  outb      = (_Float16*)(ws + 38400000);    // 6.4 MB
  float*     sums      = (float*)(ws + 44800000);       // 0.4 MB
  char*      recs      = (char*)(ws + 45200000);        // 38.4 MB (24B/edge)
  int*       deg       = (int*)(ws + 83600000);         // 0.4 MB
  int*       cur       = (int*)(ws + 84000000);         // 0.4 MB
  int*       bsums     = (int*)(ws + 84400000);         // 4 KB
  _Float16*  WpreT     = (_Float16*)(ws + 84410000);    // 16 KB
  _Float16*  w2pk      = (_Float16*)(ws + 84430000);    // 4 KB
  _Float16*  w1epk     = (_Float16*)(ws + 84440000);    // 4 KB

  dim3 blk(256);
  dim3 grid_e(NE / 256);          // 6250, exact
  dim3 grid_n((NN + 255) / 256);  // 391
  dim3 grid_p((NN + 63) / 64);    // 1563
  int nscan = (NN + 1023) / 1024; // 98

  setup_kernel<<<3125, blk, 0, stream>>>(W1, W2, WpreT, w2pk, w1epk,
                                         (float4*)scattered, deg);
  hist_kernel<<<grid_e, blk, 0, stream>>>(ei, deg);
  scan1_kernel<<<nscan, blk, 0, stream>>>(deg, cur, bsums);
  scan3_kernel<<<grid_n, blk, 0, stream>>>(cur, bsums);
  fill_kernel<<<grid_e, blk, 0, stream>>>(ei, ea, cur, recs);

  init_kernel<<<grid_n, blk, 0, stream>>>(x_t, F, out, outb, sums);

  for (int k = 0; k < 2; ++k) {
    pre_kernel<<<grid_p, blk, 0, stream>>>(x_s, outb, WpreT, ABh);
    edge_kernel<<<grid_e, blk, 0, stream>>>(ABh, outb, sums, recs, b1, b2,
                                            w2pk, w1epk, scattered);
    node_kernel<<<grid_n, blk, 0, stream>>>(out, scattered,
                                            F + (size_t)(k + 1) * DF * DF,
                                            outb, sums);
  }
}